// Round 13
// baseline (333.847 us; speedup 1.0000x reference)
//
#include <hip/hip_runtime.h>
#include <math.h>

// ---------------------------------------------------------------------------
// SiameseRPN one-branch, round 13 — many small homogeneous fold streams:
//  k_fold: 9216 blocks (128 g x 9 chunks x 8 rsub), each 16 rows x 512-float
//          window; 8 nt f4 loads fully in flight per thread; LDS pair-reduce
//          -> 8 partial slabs WFP[8][128][4608]. (R9's 3.4 TB/s marginal-rate
//          config, single pass, no conv co-resident.)
//  k0    : pad target_feat; zero tP; Bfold.
//  k_conv: separate kernel, 3x3 conv partials K-split x16 -> CVP.
//  K2    : bid<256: cred (sum CVP + BN + 0.1 -> tP); else z2 (8-slab sum).
//  k3    : merged = sum t' * Z2.   k4: heads + softmax.
// Workspace: 10,426,496 floats = 41.7 MB.
// ---------------------------------------------------------------------------

#define WS_TFP 0            // 591872
#define WS_TP  591872       // 389120  -> 980992
#define WS_BF  980992       // 128     -> 981120
#define WS_WFP 981120       // 8*589824 = 4718592 -> 5699712  [slab][eh][4608]
#define WS_Z2P 5699712      // 401408  -> 6101120
#define WS_MRG 6101120      // 131072  -> 6232192
#define WS_CVP 6232192      // 16*262144 -> 10426496
#define WFP_SLAB 589824

typedef float f4u __attribute__((ext_vector_type(4), aligned(4)));
typedef float f4a __attribute__((ext_vector_type(4)));

#define FMA4(ww, vv) \
  acc.x = fmaf(ww, (vv).x, acc.x); acc.y = fmaf(ww, (vv).y, acc.y); \
  acc.z = fmaf(ww, (vv).z, acc.z); acc.w = fmaf(ww, (vv).w, acc.w)

#define NTL(p) __builtin_nontemporal_load((const f4a*)(p))

__global__ __launch_bounds__(256) void k_fold(
    const float* __restrict__ wtpl,    // w_template 16384*4608
    const float* __restrict__ wm,      // w_merge_cls 256
    float* ws)
{
  // block: g in [0,128), chunk in [0,9), rsub in [0,8). 16 rows per block.
  const int b = blockIdx.x;
  const int g = b / 72, rest = b % 72;
  const int chunk = rest / 8, rsub = rest % 8;
  const int tid = threadIdx.x;
  const int colv = tid & 127, rowg = tid >> 7;
  const int c0 = chunk * 512 + colv * 4;
  const int row0 = g * 128 + rsub * 16 + rowg * 8;
  const float* base = wtpl + (size_t)row0 * 4608 + c0;
  const float* wmb = wm + (g & 1) * 128 + rsub * 16 + rowg * 8;
  f4a acc = {0.f, 0.f, 0.f, 0.f};
  // 8 rows, all loads in flight simultaneously
  const f4a v0 = NTL(base);
  const f4a v1 = NTL(base + 1 * 4608);
  const f4a v2 = NTL(base + 2 * 4608);
  const f4a v3 = NTL(base + 3 * 4608);
  const f4a v4 = NTL(base + 4 * 4608);
  const f4a v5 = NTL(base + 5 * 4608);
  const f4a v6 = NTL(base + 6 * 4608);
  const f4a v7 = NTL(base + 7 * 4608);
  const float w0 = wmb[0], w1 = wmb[1], w2 = wmb[2], w3 = wmb[3];
  const float w4 = wmb[4], w5 = wmb[5], w6 = wmb[6], w7 = wmb[7];
  FMA4(w0, v0); FMA4(w1, v1); FMA4(w2, v2); FMA4(w3, v3);
  FMA4(w4, v4); FMA4(w5, v5); FMA4(w6, v6); FMA4(w7, v7);
  __shared__ f4a red[128];
  if (rowg) red[colv] = acc;
  __syncthreads();
  if (!rowg) {
    const f4a o = red[colv];
    acc.x += o.x; acc.y += o.y; acc.z += o.z; acc.w += o.w;
    float* wp = ws + WS_WFP + (size_t)rsub * WFP_SLAB + (size_t)g * 4608;
    *(f4a*)(wp + c0) = acc;
  }
}

__global__ __launch_bounds__(256) void k0_prep(
    const float* __restrict__ tfeat,   // target_feat 512*32*32
    const float* __restrict__ wm,      // w_merge_cls 256
    const float* __restrict__ btpl,    // b_template 16384
    float* ws)
{
  const int N0 = 591872, N2 = 389120;
  const int total = N0 + N2;
  for (int idx = blockIdx.x * 256 + threadIdx.x; idx < total + 128; idx += gridDim.x * 256) {
    if (idx < N0) {
      int ci = idx / 1156, r = idx % 1156;
      int yy = r / 34, xx = r % 34;
      float v = 0.f;
      if (yy >= 1 && yy <= 32 && xx >= 1 && xx <= 32)
        v = tfeat[ci * 1024 + (yy - 1) * 32 + (xx - 1)];
      ws[WS_TFP + idx] = v;
    } else if (idx < total) {
      ws[WS_TP + (idx - N0)] = 0.f;
    } else {
      const int eh = idx - total;
      const int e = eh >> 1, h = eh & 1;
      const float* wmp = wm + h * 128;
      const float* bp = btpl + e * 256 + h * 128;
      float s = 0.f;
      for (int cl = 0; cl < 128; cl++) s = fmaf(wmp[cl], bp[cl], s);
      ws[WS_BF + eh] = s;
    }
  }
}

__global__ __launch_bounds__(256) void k_conv(
    const float* __restrict__ wtgt,    // w_target 256*512*9
    float* ws)
{
  // grid: coblk(16) x pxblk(16) x ks(8); thread: ksub(2) x cog(4) x pxg(32)
  const int bid = blockIdx.x;
  const int coblk = bid >> 7, pxblk = (bid >> 3) & 15, ks = bid & 7;
  const int tid = threadIdx.x;
  const int ksub = tid >> 7, sub = tid & 127;
  const int cog = sub >> 5, pxg = sub & 31;
  const int row = pxg >> 4, x0 = (pxg & 15) * 2;
  const int y = pxblk * 2 + row;
  const int co0 = coblk * 16 + cog * 4;
  const int ci0 = ks * 64 + ksub * 32;
  const float* tfp = ws + WS_TFP;

  float acc[4][2] = {{0.f, 0.f}, {0.f, 0.f}, {0.f, 0.f}, {0.f, 0.f}};
  for (int i = 0; i < 32; i++) {
    const int ci = ci0 + i;
    const float* tin = tfp + (size_t)ci * 1156 + y * 34 + x0;
    const f4u p0 = *(const f4u*)(tin);
    const f4u p1 = *(const f4u*)(tin + 34);
    const f4u p2 = *(const f4u*)(tin + 68);
    #pragma unroll
    for (int c = 0; c < 4; c++) {
      const float* wr = wtgt + (size_t)(co0 + c) * 4608 + ci * 9;
      const f4u wa = *(const f4u*)(wr);
      const f4u wb = *(const f4u*)(wr + 4);
      const float w8 = wr[8];
      acc[c][0] += wa.x * p0.x + wa.y * p0.y + wa.z * p0.z
                 + wa.w * p1.x + wb.x * p1.y + wb.y * p1.z
                 + wb.z * p2.x + wb.w * p2.y + w8 * p2.z;
      acc[c][1] += wa.x * p0.y + wa.y * p0.z + wa.z * p0.w
                 + wa.w * p1.y + wb.x * p1.z + wb.y * p1.w
                 + wb.z * p2.y + wb.w * p2.z + w8 * p2.w;
    }
  }
  float* cvp = ws + WS_CVP + (size_t)(ks * 2 + ksub) * 262144;
  #pragma unroll
  for (int c = 0; c < 4; c++) {
    cvp[(co0 + c) * 1024 + y * 32 + x0 + 0] = acc[c][0];
    cvp[(co0 + c) * 1024 + y * 32 + x0 + 1] = acc[c][1];
  }
}

__global__ __launch_bounds__(256) void K2_cred_z2(
    const float* __restrict__ btgt,
    const float* __restrict__ gamma, const float* __restrict__ beta,
    const float* __restrict__ mean, const float* __restrict__ var,
    const float* __restrict__ zfeat,    // template_feat 2*512*49
    float* ws)
{
  __shared__ float Tl[50][144];
  const int tid = threadIdx.x;
  if (blockIdx.x < 256) {
    const int co = blockIdx.x;
    const float sc = gamma[co] * rsqrtf(var[co] + 1e-5f);
    const float off = btgt[co] - mean[co];
    const float bt = beta[co];
    const float* cvp = ws + WS_CVP + (size_t)co * 1024;
    float* tP = ws + WS_TP;
    #pragma unroll
    for (int k = 0; k < 4; k++) {
      const int j = k * 256 + tid;
      float s = 0.f;
      #pragma unroll
      for (int sl = 0; sl < 16; sl++) s += cvp[(size_t)sl * 262144 + j];
      const float t = ((s + off) * sc + bt) * 0.1f;
      const int yy = j >> 5, xx = j & 31;
      tP[co * 1520 + (yy + 3) * 40 + (xx + 3)] = t;
    }
  } else {
    const int b2 = blockIdx.x - 256;
    const int n = b2 >> 5, kc = b2 & 31;
    const int ci0 = kc * 16;
    for (int idx = tid; idx < 7200; idx += 256) {
      const int uv = idx / 144, kk = idx % 144;
      float v = 0.f;
      if (uv < 49) {
        const int u = uv / 7, vv = uv % 7;
        const int ci = ci0 + kk / 9, pq = kk % 9;
        const int p = pq / 3, q2 = pq % 3;
        const int yy = u + p - 1, xx = vv + q2 - 1;
        if (yy >= 0 && yy < 7 && xx >= 0 && xx < 7)
          v = zfeat[n * 25088 + ci * 49 + yy * 7 + xx];
      }
      Tl[uv][kk] = v;
    }
    __syncthreads();
    const int ehq = tid & 31, uvg = tid >> 5;
    const int eh0 = ehq * 4;
    const int uv0 = (uvg == 0) ? 0 : uvg * 6 + 1;
    const float* wfp = ws + WS_WFP;
    float4 acc[7];
    #pragma unroll
    for (int i = 0; i < 7; i++) acc[i] = make_float4(0.f, 0.f, 0.f, 0.f);
    for (int g = 0; g < 36; g++) {
      const int koff = ci0 * 9 + g * 4;
      f4a wvE[4];
      #pragma unroll
      for (int e = 0; e < 4; e++) {
        const float* pe = wfp + (size_t)(eh0 + e) * 4608 + koff;
        f4a a = *(const f4a*)(pe);
        #pragma unroll
        for (int sl = 1; sl < 8; sl++)
          a += *(const f4a*)(pe + (size_t)sl * WFP_SLAB);
        wvE[e] = a;
      }
      #pragma unroll
      for (int uu = 0; uu < 7; uu++) {
        const float4 t4 = *(const float4*)(&Tl[uv0 + uu][g * 4]);
        acc[uu].x = fmaf(t4.x, wvE[0].x, fmaf(t4.y, wvE[0].y, fmaf(t4.z, wvE[0].z, fmaf(t4.w, wvE[0].w, acc[uu].x))));
        acc[uu].y = fmaf(t4.x, wvE[1].x, fmaf(t4.y, wvE[1].y, fmaf(t4.z, wvE[1].z, fmaf(t4.w, wvE[1].w, acc[uu].y))));
        acc[uu].z = fmaf(t4.x, wvE[2].x, fmaf(t4.y, wvE[2].y, fmaf(t4.z, wvE[2].z, fmaf(t4.w, wvE[2].w, acc[uu].z))));
        acc[uu].w = fmaf(t4.x, wvE[3].x, fmaf(t4.y, wvE[3].y, fmaf(t4.z, wvE[3].z, fmaf(t4.w, wvE[3].w, acc[uu].w))));
      }
    }
    float* z2p = ws + WS_Z2P;
    #pragma unroll
    for (int uu = 0; uu < 7; uu++) {
      const int uv = uv0 + uu;
      if (uv <= 48)
        *(float4*)(z2p + ((size_t)((n * 32 + kc) * 49 + uv)) * 128 + eh0) = acc[uu];
    }
  }
}

__global__ __launch_bounds__(128) void k3_merged(float* ws)
{
  __shared__ float Z2s[16][7][8];
  const int tid = threadIdx.x;
  const int bid = blockIdx.x;
  const int n = bid >> 7, rest = bid & 127;
  const int ec = rest >> 4, hq = rest & 15;
  const int c0 = ec * 16, h0 = hq * 2;
  const float* z2p = ws + WS_Z2P;
  const float* bf = ws + WS_BF;
  for (int idx = tid; idx < 784; idx += 128) {
    const int cl = idx & 15, uv = idx >> 4;
    float s = bf[c0 + cl];
    const float* p = z2p + (size_t)(n * 1568 + uv) * 128 + (c0 + cl);
    #pragma unroll 8
    for (int kc = 0; kc < 32; kc++) s += p[(size_t)kc * 6272];
    Z2s[cl][uv / 7][uv % 7] = s;
  }
  for (int idx = tid; idx < 112; idx += 128)
    Z2s[idx / 7][idx % 7][7] = 0.f;
  __syncthreads();

  const int e = tid >> 4, row = (tid >> 3) & 1, wq = tid & 7;
  const int w0 = wq * 4;
  const float* tP = ws + WS_TP;
  float acc[4] = {0.f, 0.f, 0.f, 0.f};
  #pragma unroll
  for (int h128 = 0; h128 < 2; h128++) {
    const int cl = 2 * e + h128;
    const float* tc = tP + (size_t)(128 * n + c0 + cl) * 1520;
    #pragma unroll
    for (int u = 0; u < 7; u++) {
      const float* trow = tc + (h0 + row + u) * 40 + w0;
      float tw[12];
      *(float4*)&tw[0] = *(const float4*)(trow);
      *(float4*)&tw[4] = *(const float4*)(trow + 4);
      *(float4*)&tw[8] = *(const float4*)(trow + 8);
      float z[8];
      *(float4*)&z[0] = *(const float4*)&Z2s[cl][u][0];
      *(float4*)&z[4] = *(const float4*)&Z2s[cl][u][4];
      #pragma unroll
      for (int px = 0; px < 4; px++)
        #pragma unroll
        for (int v = 0; v < 8; v++)
          acc[px] = fmaf(z[v], tw[px + v], acc[px]);
    }
  }
  float* mrg = ws + WS_MRG;
  *(float4*)(mrg + (size_t)(((n * 64 + ec * 8 + e) * 32) + h0 + row) * 32 + w0) =
      make_float4(acc[0], acc[1], acc[2], acc[3]);
}

__global__ __launch_bounds__(256) void k4_heads(
    const float* __restrict__ cb,
    const float* __restrict__ wcls, const float* __restrict__ bcls,
    const float* __restrict__ wbox, const float* __restrict__ bbox,
    float* ws, float* __restrict__ out)
{
  __shared__ float mrg_l[32][66];
  __shared__ float wcb_l[54][64];
  __shared__ float bias_l[54];
  __shared__ float logits[18][32];
  const int tid = threadIdx.x;
  const int n = blockIdx.x >> 5, h = blockIdx.x & 31;
  const float* mrg = ws + WS_MRG;
  for (int idx = tid; idx < 2048; idx += 256) {
    const int e = idx >> 5, w = idx & 31;
    mrg_l[w][e] = mrg[(size_t)(((n * 64 + e) * 32) + h) * 32 + w] + cb[e];
  }
  for (int idx = tid; idx < 3456; idx += 256) {
    const int ch = idx >> 6, e = idx & 63;
    wcb_l[ch][e] = (ch < 18) ? wcls[ch * 64 + e] : wbox[(ch - 18) * 64 + e];
  }
  if (tid < 54) bias_l[tid] = (tid < 18) ? bcls[tid] : bbox[tid - 18];
  __syncthreads();

  const int w = tid & 31, chg = tid >> 5;
  const int cnt = (chg < 6) ? 7 : 6;
  float acc[7] = {0.f, 0.f, 0.f, 0.f, 0.f, 0.f, 0.f};
  for (int e2 = 0; e2 < 32; e2++) {
    const float2 m2 = *(const float2*)&mrg_l[w][e2 * 2];
    #pragma unroll
    for (int i = 0; i < 7; i++) {
      if (i < cnt) {
        const int ch = chg + 8 * i;
        const float2 wv = *(const float2*)&wcb_l[ch][e2 * 2];
        acc[i] = fmaf(m2.x, wv.x, acc[i]);
        acc[i] = fmaf(m2.y, wv.y, acc[i]);
      }
    }
  }
  #pragma unroll
  for (int i = 0; i < 7; i++) {
    if (i < cnt) {
      const int ch = chg + 8 * i;
      const float v = acc[i] + bias_l[ch];
      if (ch < 18) logits[ch][w] = v;
      else out[36864 + n * 36864 + (ch - 18) * 1024 + h * 32 + w] = v;
    }
  }
  __syncthreads();
  for (int idx = tid; idx < 576; idx += 256) {
    const int ch = idx >> 5, w2 = idx & 31;
    const float a = logits[ch][w2];
    const float b = logits[(ch + 9) % 18][w2];
    const float m = fmaxf(a, b);
    const float ea = expf(a - m), eb = expf(b - m);
    out[n * 18432 + ch * 1024 + h * 32 + w2] = ea / (ea + eb);
  }
}

extern "C" void kernel_launch(void* const* d_in, const int* in_sizes, int n_in,
                              void* d_out, int out_size, void* d_ws, size_t ws_size,
                              hipStream_t stream) {
  (void)in_sizes; (void)n_in; (void)out_size; (void)ws_size;
  const float* target_feat   = (const float*)d_in[0];
  const float* template_feat = (const float*)d_in[1];
  const float* w_target      = (const float*)d_in[2];
  const float* b_target      = (const float*)d_in[3];
  const float* bn_gamma      = (const float*)d_in[4];
  const float* bn_beta       = (const float*)d_in[5];
  const float* bn_mean       = (const float*)d_in[6];
  const float* bn_var        = (const float*)d_in[7];
  const float* w_template    = (const float*)d_in[8];
  const float* b_template    = (const float*)d_in[9];
  const float* w_merge       = (const float*)d_in[10];
  const float* corr_bias     = (const float*)d_in[11];
  const float* w_cls         = (const float*)d_in[12];
  const float* b_cls         = (const float*)d_in[13];
  const float* w_box         = (const float*)d_in[14];
  const float* b_box         = (const float*)d_in[15];
  float* ws = (float*)d_ws;
  float* out = (float*)d_out;

  hipLaunchKernelGGL(k_fold, dim3(9216), dim3(256), 0, stream,
                     w_template, w_merge, ws);
  hipLaunchKernelGGL(k0_prep, dim3(2048), dim3(256), 0, stream,
                     target_feat, w_merge, b_template, ws);
  hipLaunchKernelGGL(k_conv, dim3(2048), dim3(256), 0, stream,
                     w_target, ws);
  hipLaunchKernelGGL(K2_cred_z2, dim3(320), dim3(256), 0, stream,
                     b_target, bn_gamma, bn_beta, bn_mean, bn_var,
                     template_feat, ws);
  hipLaunchKernelGGL(k3_merged, dim3(256), dim3(128), 0, stream, ws);
  hipLaunchKernelGGL(k4_heads, dim3(64), dim3(256), 0, stream,
                     corr_bias, w_cls, b_cls, w_box, b_box, ws, out);
}

// Round 15
// 231.886 us; speedup vs baseline: 1.4397x; 1.4397x over previous
//
#include <hip/hip_runtime.h>
#include <math.h>
#include <stdint.h>

// ---------------------------------------------------------------------------
// SiameseRPN one-branch, round 15 (= round 14 resubmit, infra failure):
//  k_fold: 1152 blocks (128 g x 9 chunks). Per block: 128 rows x 512-col
//          window reduced in 8 stages of 16 rows; each stage staged to LDS
//          via __builtin_amdgcn_global_load_lds (16B/lane, 8 calls/wave),
//          double-buffered with s_waitcnt vmcnt(8). Full 128-row sum in
//          block -> single slab WFP[128 eh][4608 k].
//  k0    : pad target_feat; zero tP; Bfold.        (R7 verbatim)
//  k_conv: 3x3 conv partials K-split x16 -> CVP.   (R7 verbatim)
//  k_cred: sum 16 slabs + BN + 0.1 -> tP.          (R7 verbatim)
//  k2_z2 : Z2 partials, single-slab row-major WFP. (R8 form, 1 slab)
//  k3/k4 : unchanged.
// Workspace: 6,297,728 floats = 25.2 MB.
// ---------------------------------------------------------------------------

#define WS_TFP 0            // 591872
#define WS_TP  591872       // 389120  -> 980992
#define WS_BF  980992       // 128     -> 981120
#define WS_WFP 981120       // 589824  -> 1570944   layout: [eh][4608]
#define WS_Z2P 1570944      // 401408  -> 1972352
#define WS_MRG 1972352      // 131072  -> 2103424
#define WS_CVP 2103424      // 16*262144 -> 6297728

typedef float f4u __attribute__((ext_vector_type(4), aligned(4)));
typedef float f4a __attribute__((ext_vector_type(4)));

__global__ __launch_bounds__(256) void k_fold(
    const float* __restrict__ wtpl,    // w_template 16384*4608
    const float* __restrict__ wm,      // w_merge_cls 256
    float* ws)
{
  // block: g in [0,128), chunk in [0,9)
  const int g = blockIdx.x / 9, chunk = blockIdx.x % 9;
  const int tid = threadIdx.x;
  const int wid = tid >> 6, lane = tid & 63;
  __shared__ float st[2][8192];      // 2 x 16 rows x 512 floats = 64 KB
  __shared__ float wS[128];
  if (tid < 128) wS[tid] = wm[(g & 1) * 128 + tid];
  const float* gbase = wtpl + (size_t)(g * 128) * 4608 + chunk * 512;

  // stage s (16 rows) into buf: 8 global_load_lds calls per wave, 1KB each
  auto issue_stage = [&](int buf, int s) {
    const float* sb = gbase + (size_t)(s * 16) * 4608;
    #pragma unroll
    for (int i = 0; i < 8; i++) {
      const int call = wid * 8 + i;
      const int row = call >> 1, half = call & 1;
      const float* src = sb + (size_t)row * 4608 + half * 256 + lane * 4;
      float* dst = &st[buf][row * 512 + half * 256];
      __builtin_amdgcn_global_load_lds((const uint32_t*)src, (uint32_t*)dst,
                                       16, 0, 0);
    }
  };

  issue_stage(0, 0);
  float accx = 0.f, accy = 0.f;
  for (int s = 0; s < 8; s++) {
    if (s < 7) {
      issue_stage((s + 1) & 1, s + 1);
      asm volatile("s_waitcnt vmcnt(8)" ::: "memory");
    } else {
      asm volatile("s_waitcnt vmcnt(0)" ::: "memory");
    }
    __syncthreads();
    const float* buf = st[s & 1];
    #pragma unroll
    for (int r = 0; r < 16; r++) {
      const float wgt = wS[s * 16 + r];
      accx = fmaf(wgt, buf[r * 512 + tid], accx);
      accy = fmaf(wgt, buf[r * 512 + 256 + tid], accy);
    }
    __syncthreads();
  }
  float* wp = ws + WS_WFP + (size_t)g * 4608 + chunk * 512;
  wp[tid] = accx;
  wp[tid + 256] = accy;
}

__global__ __launch_bounds__(256) void k0_prep(
    const float* __restrict__ tfeat,   // target_feat 512*32*32
    const float* __restrict__ wm,      // w_merge_cls 256
    const float* __restrict__ btpl,    // b_template 16384
    float* ws)
{
  const int N0 = 591872, N2 = 389120;
  const int total = N0 + N2;
  for (int idx = blockIdx.x * 256 + threadIdx.x; idx < total + 128; idx += gridDim.x * 256) {
    if (idx < N0) {
      int ci = idx / 1156, r = idx % 1156;
      int yy = r / 34, xx = r % 34;
      float v = 0.f;
      if (yy >= 1 && yy <= 32 && xx >= 1 && xx <= 32)
        v = tfeat[ci * 1024 + (yy - 1) * 32 + (xx - 1)];
      ws[WS_TFP + idx] = v;
    } else if (idx < total) {
      ws[WS_TP + (idx - N0)] = 0.f;
    } else {
      const int eh = idx - total;
      const int e = eh >> 1, h = eh & 1;
      const float* wmp = wm + h * 128;
      const float* bp = btpl + e * 256 + h * 128;
      float s = 0.f;
      for (int cl = 0; cl < 128; cl++) s = fmaf(wmp[cl], bp[cl], s);
      ws[WS_BF + eh] = s;
    }
  }
}

__global__ __launch_bounds__(256) void k_conv(
    const float* __restrict__ wtgt,    // w_target 256*512*9
    float* ws)
{
  // grid: coblk(16) x pxblk(16) x ks(8); thread: ksub(2) x cog(4) x pxg(32)
  const int bid = blockIdx.x;
  const int coblk = bid >> 7, pxblk = (bid >> 3) & 15, ks = bid & 7;
  const int tid = threadIdx.x;
  const int ksub = tid >> 7, sub = tid & 127;
  const int cog = sub >> 5, pxg = sub & 31;
  const int row = pxg >> 4, x0 = (pxg & 15) * 2;
  const int y = pxblk * 2 + row;
  const int co0 = coblk * 16 + cog * 4;
  const int ci0 = ks * 64 + ksub * 32;
  const float* tfp = ws + WS_TFP;

  float acc[4][2] = {{0.f, 0.f}, {0.f, 0.f}, {0.f, 0.f}, {0.f, 0.f}};
  for (int i = 0; i < 32; i++) {
    const int ci = ci0 + i;
    const float* tin = tfp + (size_t)ci * 1156 + y * 34 + x0;
    const f4u p0 = *(const f4u*)(tin);
    const f4u p1 = *(const f4u*)(tin + 34);
    const f4u p2 = *(const f4u*)(tin + 68);
    #pragma unroll
    for (int c = 0; c < 4; c++) {
      const float* wr = wtgt + (size_t)(co0 + c) * 4608 + ci * 9;
      const f4u wa = *(const f4u*)(wr);
      const f4u wb = *(const f4u*)(wr + 4);
      const float w8 = wr[8];
      acc[c][0] += wa.x * p0.x + wa.y * p0.y + wa.z * p0.z
                 + wa.w * p1.x + wb.x * p1.y + wb.y * p1.z
                 + wb.z * p2.x + wb.w * p2.y + w8 * p2.z;
      acc[c][1] += wa.x * p0.y + wa.y * p0.z + wa.z * p0.w
                 + wa.w * p1.y + wb.x * p1.z + wb.y * p1.w
                 + wb.z * p2.y + wb.w * p2.z + w8 * p2.w;
    }
  }
  float* cvp = ws + WS_CVP + (size_t)(ks * 2 + ksub) * 262144;
  #pragma unroll
  for (int c = 0; c < 4; c++) {
    cvp[(co0 + c) * 1024 + y * 32 + x0 + 0] = acc[c][0];
    cvp[(co0 + c) * 1024 + y * 32 + x0 + 1] = acc[c][1];
  }
}

__global__ __launch_bounds__(256) void k_cred(
    const float* __restrict__ btgt,
    const float* __restrict__ gamma, const float* __restrict__ beta,
    const float* __restrict__ mean, const float* __restrict__ var,
    float* ws)
{
  const int co = blockIdx.x;
  const int tid = threadIdx.x;
  const float sc = gamma[co] * rsqrtf(var[co] + 1e-5f);
  const float off = btgt[co] - mean[co];
  const float bt = beta[co];
  const float* cvp = ws + WS_CVP + (size_t)co * 1024;
  float* tP = ws + WS_TP;
  #pragma unroll
  for (int k = 0; k < 4; k++) {
    const int j = k * 256 + tid;
    float s = 0.f;
    #pragma unroll
    for (int sl = 0; sl < 16; sl++) s += cvp[(size_t)sl * 262144 + j];
    const float t = ((s + off) * sc + bt) * 0.1f;
    const int yy = j >> 5, xx = j & 31;
    tP[co * 1520 + (yy + 3) * 40 + (xx + 3)] = t;
  }
}

__global__ __launch_bounds__(256) void k2_z2(
    const float* __restrict__ zfeat,    // template_feat 2*512*49
    float* ws)
{
  __shared__ float Tl[50][144];
  const int tid = threadIdx.x;
  const int n = blockIdx.x >> 5, kc = blockIdx.x & 31;
  const int ci0 = kc * 16;
  for (int idx = tid; idx < 7200; idx += 256) {
    const int uv = idx / 144, kk = idx % 144;
    float v = 0.f;
    if (uv < 49) {
      const int u = uv / 7, vv = uv % 7;
      const int ci = ci0 + kk / 9, pq = kk % 9;
      const int p = pq / 3, q = pq % 3;
      const int yy = u + p - 1, xx = vv + q - 1;
      if (yy >= 0 && yy < 7 && xx >= 0 && xx < 7)
        v = zfeat[n * 25088 + ci * 49 + yy * 7 + xx];
    }
    Tl[uv][kk] = v;
  }
  __syncthreads();
  const int ehq = tid & 31, uvg = tid >> 5;
  const int eh0 = ehq * 4;
  const int uv0 = (uvg == 0) ? 0 : uvg * 6 + 1;
  const float* wfp = ws + WS_WFP;
  float4 acc[7];
  #pragma unroll
  for (int i = 0; i < 7; i++) acc[i] = make_float4(0.f, 0.f, 0.f, 0.f);
  for (int g = 0; g < 36; g++) {
    const int koff = ci0 * 9 + g * 4;
    f4a wvE[4];
    #pragma unroll
    for (int e = 0; e < 4; e++) {
      const float* pe = wfp + (size_t)(eh0 + e) * 4608 + koff;
      wvE[e] = *(const f4a*)(pe);
    }
    #pragma unroll
    for (int uu = 0; uu < 7; uu++) {
      const float4 t4 = *(const float4*)(&Tl[uv0 + uu][g * 4]);
      acc[uu].x = fmaf(t4.x, wvE[0].x, fmaf(t4.y, wvE[0].y, fmaf(t4.z, wvE[0].z, fmaf(t4.w, wvE[0].w, acc[uu].x))));
      acc[uu].y = fmaf(t4.x, wvE[1].x, fmaf(t4.y, wvE[1].y, fmaf(t4.z, wvE[1].z, fmaf(t4.w, wvE[1].w, acc[uu].y))));
      acc[uu].z = fmaf(t4.x, wvE[2].x, fmaf(t4.y, wvE[2].y, fmaf(t4.z, wvE[2].z, fmaf(t4.w, wvE[2].w, acc[uu].z))));
      acc[uu].w = fmaf(t4.x, wvE[3].x, fmaf(t4.y, wvE[3].y, fmaf(t4.z, wvE[3].z, fmaf(t4.w, wvE[3].w, acc[uu].w))));
    }
  }
  float* z2p = ws + WS_Z2P;
  #pragma unroll
  for (int uu = 0; uu < 7; uu++) {
    const int uv = uv0 + uu;
    if (uv <= 48)
      *(float4*)(z2p + ((size_t)((n * 32 + kc) * 49 + uv)) * 128 + eh0) = acc[uu];
  }
}

__global__ __launch_bounds__(128) void k3_merged(float* ws)
{
  __shared__ float Z2s[16][7][8];
  const int tid = threadIdx.x;
  const int bid = blockIdx.x;
  const int n = bid >> 7, rest = bid & 127;
  const int ec = rest >> 4, hq = rest & 15;
  const int c0 = ec * 16, h0 = hq * 2;
  const float* z2p = ws + WS_Z2P;
  const float* bf = ws + WS_BF;
  for (int idx = tid; idx < 784; idx += 128) {
    const int cl = idx & 15, uv = idx >> 4;
    float s = bf[c0 + cl];
    const float* p = z2p + (size_t)(n * 1568 + uv) * 128 + (c0 + cl);
    #pragma unroll 8
    for (int kc = 0; kc < 32; kc++) s += p[(size_t)kc * 6272];
    Z2s[cl][uv / 7][uv % 7] = s;
  }
  for (int idx = tid; idx < 112; idx += 128)
    Z2s[idx / 7][idx % 7][7] = 0.f;
  __syncthreads();

  const int e = tid >> 4, row = (tid >> 3) & 1, wq = tid & 7;
  const int w0 = wq * 4;
  const float* tP = ws + WS_TP;
  float acc[4] = {0.f, 0.f, 0.f, 0.f};
  #pragma unroll
  for (int h128 = 0; h128 < 2; h128++) {
    const int cl = 2 * e + h128;
    const float* tc = tP + (size_t)(128 * n + c0 + cl) * 1520;
    #pragma unroll
    for (int u = 0; u < 7; u++) {
      const float* trow = tc + (h0 + row + u) * 40 + w0;
      float tw[12];
      *(float4*)&tw[0] = *(const float4*)(trow);
      *(float4*)&tw[4] = *(const float4*)(trow + 4);
      *(float4*)&tw[8] = *(const float4*)(trow + 8);
      float z[8];
      *(float4*)&z[0] = *(const float4*)&Z2s[cl][u][0];
      *(float4*)&z[4] = *(const float4*)&Z2s[cl][u][4];
      #pragma unroll
      for (int px = 0; px < 4; px++)
        #pragma unroll
        for (int v = 0; v < 8; v++)
          acc[px] = fmaf(z[v], tw[px + v], acc[px]);
    }
  }
  float* mrg = ws + WS_MRG;
  *(float4*)(mrg + (size_t)(((n * 64 + ec * 8 + e) * 32) + h0 + row) * 32 + w0) =
      make_float4(acc[0], acc[1], acc[2], acc[3]);
}

__global__ __launch_bounds__(256) void k4_heads(
    const float* __restrict__ cb,
    const float* __restrict__ wcls, const float* __restrict__ bcls,
    const float* __restrict__ wbox, const float* __restrict__ bbox,
    float* ws, float* __restrict__ out)
{
  __shared__ float mrg_l[32][66];
  __shared__ float wcb_l[54][64];
  __shared__ float bias_l[54];
  __shared__ float logits[18][32];
  const int tid = threadIdx.x;
  const int n = blockIdx.x >> 5, h = blockIdx.x & 31;
  const float* mrg = ws + WS_MRG;
  for (int idx = tid; idx < 2048; idx += 256) {
    const int e = idx >> 5, w = idx & 31;
    mrg_l[w][e] = mrg[(size_t)(((n * 64 + e) * 32) + h) * 32 + w] + cb[e];
  }
  for (int idx = tid; idx < 3456; idx += 256) {
    const int ch = idx >> 6, e = idx & 63;
    wcb_l[ch][e] = (ch < 18) ? wcls[ch * 64 + e] : wbox[(ch - 18) * 64 + e];
  }
  if (tid < 54) bias_l[tid] = (tid < 18) ? bcls[tid] : bbox[tid - 18];
  __syncthreads();

  const int w = tid & 31, chg = tid >> 5;
  const int cnt = (chg < 6) ? 7 : 6;
  float acc[7] = {0.f, 0.f, 0.f, 0.f, 0.f, 0.f, 0.f};
  for (int e2 = 0; e2 < 32; e2++) {
    const float2 m2 = *(const float2*)&mrg_l[w][e2 * 2];
    #pragma unroll
    for (int i = 0; i < 7; i++) {
      if (i < cnt) {
        const int ch = chg + 8 * i;
        const float2 wv = *(const float2*)&wcb_l[ch][e2 * 2];
        acc[i] = fmaf(m2.x, wv.x, acc[i]);
        acc[i] = fmaf(m2.y, wv.y, acc[i]);
      }
    }
  }
  #pragma unroll
  for (int i = 0; i < 7; i++) {
    if (i < cnt) {
      const int ch = chg + 8 * i;
      const float v = acc[i] + bias_l[ch];
      if (ch < 18) logits[ch][w] = v;
      else out[36864 + n * 36864 + (ch - 18) * 1024 + h * 32 + w] = v;
    }
  }
  __syncthreads();
  for (int idx = tid; idx < 576; idx += 256) {
    const int ch = idx >> 5, w2 = idx & 31;
    const float a = logits[ch][w2];
    const float b = logits[(ch + 9) % 18][w2];
    const float m = fmaxf(a, b);
    const float ea = expf(a - m), eb = expf(b - m);
    out[n * 18432 + ch * 1024 + h * 32 + w2] = ea / (ea + eb);
  }
}

extern "C" void kernel_launch(void* const* d_in, const int* in_sizes, int n_in,
                              void* d_out, int out_size, void* d_ws, size_t ws_size,
                              hipStream_t stream) {
  (void)in_sizes; (void)n_in; (void)out_size; (void)ws_size;
  const float* target_feat   = (const float*)d_in[0];
  const float* template_feat = (const float*)d_in[1];
  const float* w_target      = (const float*)d_in[2];
  const float* b_target      = (const float*)d_in[3];
  const float* bn_gamma      = (const float*)d_in[4];
  const float* bn_beta       = (const float*)d_in[5];
  const float* bn_mean       = (const float*)d_in[6];
  const float* bn_var        = (const float*)d_in[7];
  const float* w_template    = (const float*)d_in[8];
  const float* b_template    = (const float*)d_in[9];
  const float* w_merge       = (const float*)d_in[10];
  const float* corr_bias     = (const float*)d_in[11];
  const float* w_cls         = (const float*)d_in[12];
  const float* b_cls         = (const float*)d_in[13];
  const float* w_box         = (const float*)d_in[14];
  const float* b_box         = (const float*)d_in[15];
  float* ws = (float*)d_ws;
  float* out = (float*)d_out;

  hipLaunchKernelGGL(k_fold, dim3(1152), dim3(256), 0, stream,
                     w_template, w_merge, ws);
  hipLaunchKernelGGL(k0_prep, dim3(2048), dim3(256), 0, stream,
                     target_feat, w_merge, b_template, ws);
  hipLaunchKernelGGL(k_conv, dim3(2048), dim3(256), 0, stream,
                     w_target, ws);
  hipLaunchKernelGGL(k_cred, dim3(256), dim3(256), 0, stream,
                     b_target, bn_gamma, bn_beta, bn_mean, bn_var, ws);
  hipLaunchKernelGGL(k2_z2, dim3(64), dim3(256), 0, stream,
                     template_feat, ws);
  hipLaunchKernelGGL(k3_merged, dim3(256), dim3(128), 0, stream, ws);
  hipLaunchKernelGGL(k4_heads, dim3(64), dim3(256), 0, stream,
                     corr_bias, w_cls, b_cls, w_box, b_box, ws, out);
}